// Round 1
// baseline (564.075 us; speedup 1.0000x reference)
//
#include <hip/hip_runtime.h>
#include <hip/hip_bf16.h>

#define B_ 4
#define T_ 2048
#define C_ 1024
#define H_ 16
#define D_ 64
#define SCALE_ 0.125f
#define L2E 1.4426950408889634f

typedef __attribute__((ext_vector_type(8))) short bf16x8;
typedef __attribute__((ext_vector_type(4))) float f32x4;

__device__ __forceinline__ unsigned short f2bf(float f) {
    union { float f; unsigned u; } v; v.f = f;
    unsigned r = v.u + 0x7fff + ((v.u >> 16) & 1);
    return (unsigned short)(r >> 16);
}

__device__ __forceinline__ void gl_lds16(const unsigned short* g, unsigned short* l) {
    __builtin_amdgcn_global_load_lds(
        (const __attribute__((address_space(1))) void*)g,
        (__attribute__((address_space(3))) void*)l,
        16, 0, 0);
}

// ---------------- kernel 1: hidden_states fp32 -> bf16 ----------------
__global__ void cvt_hs_kernel(const float4* __restrict__ in, ushort4* __restrict__ out) {
    int i = blockIdx.x * 256 + threadIdx.x;
    float4 v = in[i];
    ushort4 o;
    o.x = f2bf(v.x); o.y = f2bf(v.y); o.z = f2bf(v.z); o.w = f2bf(v.w);
    out[i] = o;
}

// ---------------- kernel 2: weight transpose+cast (W[k][n] -> Wt[n][k] bf16) ----
__global__ void wtrans_kernel(const float* __restrict__ Wq, const float* __restrict__ Wk,
                              const float* __restrict__ Wv, const float* __restrict__ Wo,
                              unsigned short* __restrict__ Wqkv_t, unsigned short* __restrict__ Wo_t) {
    __shared__ float tile[64][65];
    int mtx = blockIdx.y;
    const float* W = (mtx == 0) ? Wq : (mtx == 1) ? Wk : (mtx == 2) ? Wv : Wo;
    unsigned short* Out = (mtx < 3) ? (Wqkv_t + (size_t)mtx * 1024 * 1024) : Wo_t;
    int tl = blockIdx.x;
    int tx = tl & 15, ty = tl >> 4;           // tile col (n), tile row (k)
    int t = threadIdx.x;
    int col = t & 63, rb = t >> 6;
#pragma unroll
    for (int rr = 0; rr < 16; ++rr) {
        int r = rb * 16 + rr;
        tile[r][col] = W[(size_t)(ty * 64 + r) * 1024 + tx * 64 + col];
    }
    __syncthreads();
#pragma unroll
    for (int rr = 0; rr < 16; ++rr) {
        int r = rb * 16 + rr;
        Out[(size_t)(tx * 64 + r) * 1024 + ty * 64 + col] = f2bf(tile[col][r]);
    }
}

// ---------------- kernel 3: QKV GEMM (8192x1024 @ 1024x3072) ----------------
// A: bf16 8192x1024 row-major. Bt: bf16 3072x1024 (N x K). Scatters Q,K -> (b,h,t,d), V -> (b,h,d,t).
__global__ __launch_bounds__(256) void gemm_qkv_kernel(
    const unsigned short* __restrict__ A, const unsigned short* __restrict__ Bt,
    unsigned short* __restrict__ Qg, unsigned short* __restrict__ Kg, unsigned short* __restrict__ Vt) {
    __shared__ __align__(16) unsigned short As[128 * 32];
    __shared__ __align__(16) unsigned short Bs[128 * 32];
    const int tid = threadIdx.x;
    const int w = tid >> 6, lane = tid & 63;
    const int quad = lane >> 4, l16 = lane & 15;
    const int m0 = blockIdx.y * 128, n0 = blockIdx.x * 128;
    const int mw = (w >> 1) * 64, nw = (w & 1) * 64;
    const int K = 1024;
    const int srow = lane >> 2;          // 0..15
    const int scol = (lane & 3) * 8;     // 0,8,16,24

    const f32x4 fzero = {0.f, 0.f, 0.f, 0.f};
    f32x4 acc[4][4];
#pragma unroll
    for (int i = 0; i < 4; ++i)
#pragma unroll
        for (int j = 0; j < 4; ++j) acc[i][j] = fzero;

    for (int k0 = 0; k0 < K; k0 += 32) {
        gl_lds16(A + (size_t)(m0 + w * 32 + srow) * K + k0 + scol,       As + (w * 32) * 32);
        gl_lds16(A + (size_t)(m0 + w * 32 + 16 + srow) * K + k0 + scol,  As + (w * 32 + 16) * 32);
        gl_lds16(Bt + (size_t)(n0 + w * 32 + srow) * K + k0 + scol,      Bs + (w * 32) * 32);
        gl_lds16(Bt + (size_t)(n0 + w * 32 + 16 + srow) * K + k0 + scol, Bs + (w * 32 + 16) * 32);
        __syncthreads();
        bf16x8 a[4], b[4];
#pragma unroll
        for (int i = 0; i < 4; ++i)
            a[i] = *(const bf16x8*)(As + (mw + i * 16 + l16) * 32 + quad * 8);
#pragma unroll
        for (int j = 0; j < 4; ++j)
            b[j] = *(const bf16x8*)(Bs + (nw + j * 16 + l16) * 32 + quad * 8);
#pragma unroll
        for (int i = 0; i < 4; ++i)
#pragma unroll
            for (int j = 0; j < 4; ++j)
                acc[i][j] = __builtin_amdgcn_mfma_f32_16x16x32_bf16(a[i], b[j], acc[i][j], 0, 0, 0);
        __syncthreads();
    }

    // epilogue: scatter to Q (b,h,t,d), K (b,h,t,d), V^T (b,h,d,t)
#pragma unroll
    for (int j = 0; j < 4; ++j) {
        int gn = n0 + nw + j * 16 + l16;
        int tensor = gn >> 10;            // 0=Q 1=K 2=V (uniform within j-tile)
        int nl = gn & 1023;
        int hh = nl >> 6, dd = nl & 63;
#pragma unroll
        for (int i = 0; i < 4; ++i) {
            int gmb = m0 + mw + i * 16 + quad * 4;
#pragma unroll
            for (int r = 0; r < 4; ++r) {
                int m = gmb + r;
                int bb = m >> 11, tt = m & 2047;
                unsigned short v = f2bf(acc[i][j][r]);
                size_t bhh = (size_t)(bb * 16 + hh);
                if (tensor == 0)      Qg[(bhh * 2048 + tt) * 64 + dd] = v;
                else if (tensor == 1) Kg[(bhh * 2048 + tt) * 64 + dd] = v;
                else                  Vt[(bhh * 64 + dd) * 2048 + tt] = v;
            }
        }
    }
}

// ---------------- kernel 4: flash attention ----------------
// Q,K: (b,h,t,d) bf16. Vt: (b,h,d,t) bf16. AO out: (b,t,h,d) bf16.
__global__ __launch_bounds__(256) void attn_kernel(
    const unsigned short* __restrict__ Qg, const unsigned short* __restrict__ Kg,
    const unsigned short* __restrict__ Vt, const int* __restrict__ mask,
    unsigned short* __restrict__ AO) {
    __shared__ __align__(16) unsigned short Ks[32 * 64];
    __shared__ __align__(16) unsigned short Vs[64 * 32];
    __shared__ __align__(16) unsigned short Ps[4][16 * 32];
    const int tid = threadIdx.x;
    const int w = tid >> 6, lane = tid & 63;
    const int quad = lane >> 4, l16 = lane & 15;
    const int bid = blockIdx.x;
    const int bh = bid >> 5;        // 0..63
    const int qt = bid & 31;
    const int b = bh >> 4;
    const int h = bh & 15;
    const int q0 = qt * 64 + w * 16;
    const size_t bh_td = (size_t)bh * 2048 * 64;   // Q/K base
    const size_t bh_dt = (size_t)bh * 64 * 2048;   // Vt base

    const f32x4 fzero = {0.f, 0.f, 0.f, 0.f};
    bf16x8 aq0 = *(const bf16x8*)(Qg + bh_td + (size_t)(q0 + l16) * 64 + quad * 8);
    bf16x8 aq1 = *(const bf16x8*)(Qg + bh_td + (size_t)(q0 + l16) * 64 + 32 + quad * 8);

    f32x4 po[4];
#pragma unroll
    for (int j = 0; j < 4; ++j) po[j] = fzero;
    float mi[4] = {-1e30f, -1e30f, -1e30f, -1e30f};
    float li[4] = {0.f, 0.f, 0.f, 0.f};
    const int* mrow = mask + b * 2048;

    for (int k0 = 0; k0 < 2048; k0 += 32) {
        __syncthreads();   // protect K/V LDS from previous iteration readers
        gl_lds16(Kg + bh_td + (size_t)(k0 + w * 8 + (lane >> 3)) * 64 + (lane & 7) * 8,
                 Ks + w * 8 * 64);
        gl_lds16(Vt + bh_dt + (size_t)(w * 16 + (lane >> 2)) * 2048 + k0 + (lane & 3) * 8,
                 Vs + w * 16 * 32);
        __syncthreads();

        // S = Q @ K^T  (16 q-rows x 32 keys), C layout: row=q=quad*4+r, col=key=l16
        f32x4 s[2];
#pragma unroll
        for (int kt = 0; kt < 2; ++kt) {
            bf16x8 b0 = *(const bf16x8*)(Ks + (kt * 16 + l16) * 64 + quad * 8);
            bf16x8 b1 = *(const bf16x8*)(Ks + (kt * 16 + l16) * 64 + 32 + quad * 8);
            f32x4 tacc = __builtin_amdgcn_mfma_f32_16x16x32_bf16(aq0, b0, fzero, 0, 0, 0);
            s[kt] = __builtin_amdgcn_mfma_f32_16x16x32_bf16(aq1, b1, tacc, 0, 0, 0);
        }
        float msk0 = (mrow[k0 + l16] == 0) ? -1e30f : 0.f;
        float msk1 = (mrow[k0 + 16 + l16] == 0) ? -1e30f : 0.f;
#pragma unroll
        for (int r = 0; r < 4; ++r) {
            s[0][r] = s[0][r] * SCALE_ + msk0;
            s[1][r] = s[1][r] * SCALE_ + msk1;
        }
        // row max over 32 keys (cols live in 16-lane groups within quad)
        float mx[4];
#pragma unroll
        for (int r = 0; r < 4; ++r) mx[r] = fmaxf(s[0][r], s[1][r]);
#pragma unroll
        for (int d = 1; d < 16; d <<= 1)
#pragma unroll
            for (int r = 0; r < 4; ++r) mx[r] = fmaxf(mx[r], __shfl_xor(mx[r], d, 64));
        float alpha[4], rs[4];
#pragma unroll
        for (int r = 0; r < 4; ++r) {
            float mn = fmaxf(mi[r], mx[r]);
            alpha[r] = exp2f((mi[r] - mn) * L2E);
            mi[r] = mn;
            float p0 = exp2f((s[0][r] - mn) * L2E);
            float p1 = exp2f((s[1][r] - mn) * L2E);
            s[0][r] = p0; s[1][r] = p1;
            rs[r] = p0 + p1;
        }
#pragma unroll
        for (int d = 1; d < 16; d <<= 1)
#pragma unroll
            for (int r = 0; r < 4; ++r) rs[r] += __shfl_xor(rs[r], d, 64);
#pragma unroll
        for (int r = 0; r < 4; ++r) li[r] = li[r] * alpha[r] + rs[r];
#pragma unroll
        for (int j = 0; j < 4; ++j)
#pragma unroll
            for (int r = 0; r < 4; ++r) po[j][r] *= alpha[r];

        // P: C layout -> LDS -> A layout (per-wave private buffer)
#pragma unroll
        for (int kt = 0; kt < 2; ++kt)
#pragma unroll
            for (int r = 0; r < 4; ++r)
                Ps[w][(quad * 4 + r) * 32 + kt * 16 + l16] = f2bf(s[kt][r]);
        asm volatile("s_waitcnt lgkmcnt(0)" ::: "memory");
        bf16x8 ap = *(const bf16x8*)(&Ps[w][l16 * 32 + quad * 8]);
#pragma unroll
        for (int nd = 0; nd < 4; ++nd) {
            bf16x8 bv = *(const bf16x8*)(Vs + (nd * 16 + l16) * 32 + quad * 8);
            po[nd] = __builtin_amdgcn_mfma_f32_16x16x32_bf16(ap, bv, po[nd], 0, 0, 0);
        }
    }

    // epilogue: AO (b,t,h,d)
#pragma unroll
    for (int r = 0; r < 4; ++r) {
        float inv = 1.0f / li[r];
        int t = q0 + quad * 4 + r;
        size_t obase = ((size_t)(b * 2048 + t)) * 1024 + h * 64;
#pragma unroll
        for (int nd = 0; nd < 4; ++nd)
            AO[obase + nd * 16 + l16] = f2bf(po[nd][r] * inv);
    }
}

// ---------------- kernel 5: output GEMM (8192x1024 @ 1024x1024) + bias ----------------
__global__ __launch_bounds__(256) void gemm_out_kernel(
    const unsigned short* __restrict__ A, const unsigned short* __restrict__ Bt,
    const float* __restrict__ bo, float* __restrict__ out) {
    __shared__ __align__(16) unsigned short As[128 * 32];
    __shared__ __align__(16) unsigned short Bs[128 * 32];
    const int tid = threadIdx.x;
    const int w = tid >> 6, lane = tid & 63;
    const int quad = lane >> 4, l16 = lane & 15;
    const int m0 = blockIdx.y * 128, n0 = blockIdx.x * 128;
    const int mw = (w >> 1) * 64, nw = (w & 1) * 64;
    const int K = 1024;
    const int srow = lane >> 2;
    const int scol = (lane & 3) * 8;

    const f32x4 fzero = {0.f, 0.f, 0.f, 0.f};
    f32x4 acc[4][4];
#pragma unroll
    for (int i = 0; i < 4; ++i)
#pragma unroll
        for (int j = 0; j < 4; ++j) acc[i][j] = fzero;

    for (int k0 = 0; k0 < K; k0 += 32) {
        gl_lds16(A + (size_t)(m0 + w * 32 + srow) * K + k0 + scol,       As + (w * 32) * 32);
        gl_lds16(A + (size_t)(m0 + w * 32 + 16 + srow) * K + k0 + scol,  As + (w * 32 + 16) * 32);
        gl_lds16(Bt + (size_t)(n0 + w * 32 + srow) * K + k0 + scol,      Bs + (w * 32) * 32);
        gl_lds16(Bt + (size_t)(n0 + w * 32 + 16 + srow) * K + k0 + scol, Bs + (w * 32 + 16) * 32);
        __syncthreads();
        bf16x8 a[4], b[4];
#pragma unroll
        for (int i = 0; i < 4; ++i)
            a[i] = *(const bf16x8*)(As + (mw + i * 16 + l16) * 32 + quad * 8);
#pragma unroll
        for (int j = 0; j < 4; ++j)
            b[j] = *(const bf16x8*)(Bs + (nw + j * 16 + l16) * 32 + quad * 8);
#pragma unroll
        for (int i = 0; i < 4; ++i)
#pragma unroll
            for (int j = 0; j < 4; ++j)
                acc[i][j] = __builtin_amdgcn_mfma_f32_16x16x32_bf16(a[i], b[j], acc[i][j], 0, 0, 0);
        __syncthreads();
    }

#pragma unroll
    for (int j = 0; j < 4; ++j) {
        int gn = n0 + nw + j * 16 + l16;
        float bias = bo[gn];
#pragma unroll
        for (int i = 0; i < 4; ++i) {
            int gmb = m0 + mw + i * 16 + quad * 4;
#pragma unroll
            for (int r = 0; r < 4; ++r)
                out[(size_t)(gmb + r) * 1024 + gn] = acc[i][j][r] + bias;
        }
    }
}

extern "C" void kernel_launch(void* const* d_in, const int* in_sizes, int n_in,
                              void* d_out, int out_size, void* d_ws, size_t ws_size,
                              hipStream_t stream) {
    const float* hs  = (const float*)d_in[0];
    const int* mask  = (const int*)d_in[1];
    const float* Wq  = (const float*)d_in[2];
    const float* Wk  = (const float*)d_in[3];
    const float* Wv  = (const float*)d_in[4];
    const float* Wo  = (const float*)d_in[5];
    const float* bo  = (const float*)d_in[6];
    float* out = (float*)d_out;

    char* ws = (char*)d_ws;
    unsigned short* hs_bf = (unsigned short*)(ws);                  // 16 MB
    unsigned short* wqkv  = (unsigned short*)(ws + 16777216);       // 6 MB
    unsigned short* wo_t  = (unsigned short*)(ws + 23068672);       // 2 MB
    unsigned short* Qg    = (unsigned short*)(ws + 25165824);       // 16 MB
    unsigned short* Kg    = (unsigned short*)(ws + 41943040);       // 16 MB
    unsigned short* Vt    = (unsigned short*)(ws + 58720256);       // 16 MB
    unsigned short* AO    = (unsigned short*)(ws + 75497472);       // 16 MB

    cvt_hs_kernel<<<8192, 256, 0, stream>>>((const float4*)hs, (ushort4*)hs_bf);
    wtrans_kernel<<<dim3(256, 4), 256, 0, stream>>>(Wq, Wk, Wv, Wo, wqkv, wo_t);
    gemm_qkv_kernel<<<dim3(24, 64), 256, 0, stream>>>(hs_bf, wqkv, Qg, Kg, Vt);
    attn_kernel<<<2048, 256, 0, stream>>>(Qg, Kg, Vt, mask, AO);
    gemm_out_kernel<<<dim3(8, 64), 256, 0, stream>>>(AO, wo_t, bo, out);
}

// Round 2
// 358.479 us; speedup vs baseline: 1.5735x; 1.5735x over previous
//
#include <hip/hip_runtime.h>
#include <hip/hip_bf16.h>

#define B_ 4
#define T_ 2048
#define C_ 1024
#define H_ 16
#define D_ 64
#define SCALE_ 0.125f
#define L2E 1.4426950408889634f
#define SE (SCALE_ * L2E)

typedef __attribute__((ext_vector_type(8))) short bf16x8;
typedef __attribute__((ext_vector_type(4))) float f32x4;

__device__ __forceinline__ unsigned short f2bf(float f) {
    union { float f; unsigned u; } v; v.f = f;
    unsigned r = v.u + 0x7fff + ((v.u >> 16) & 1);
    return (unsigned short)(r >> 16);
}

// pack two f32 -> bf16 pair (round-half-up; inputs are probabilities in [0,1])
__device__ __forceinline__ unsigned packbf(float a, float b) {
    union { float f; unsigned u; } x, y; x.f = a; y.f = b;
    return ((x.u + 0x8000u) >> 16) | ((y.u + 0x8000u) & 0xffff0000u);
}

__device__ __forceinline__ void gl_lds16(const unsigned short* g, unsigned short* l) {
    __builtin_amdgcn_global_load_lds(
        (const __attribute__((address_space(1))) void*)g,
        (__attribute__((address_space(3))) void*)l,
        16, 0, 0);
}

// ---------------- kernel 1: hidden_states fp32 -> bf16 ----------------
__global__ void cvt_hs_kernel(const float4* __restrict__ in, ushort4* __restrict__ out) {
    int i = blockIdx.x * 256 + threadIdx.x;
    float4 v = in[i];
    ushort4 o;
    o.x = f2bf(v.x); o.y = f2bf(v.y); o.z = f2bf(v.z); o.w = f2bf(v.w);
    out[i] = o;
}

// ---------------- kernel 2: weight transpose+cast (W[k][n] -> Wt[n][k] bf16) ----
__global__ void wtrans_kernel(const float* __restrict__ Wq, const float* __restrict__ Wk,
                              const float* __restrict__ Wv, const float* __restrict__ Wo,
                              unsigned short* __restrict__ Wqkv_t, unsigned short* __restrict__ Wo_t) {
    __shared__ float tile[64][65];
    int mtx = blockIdx.y;
    const float* W = (mtx == 0) ? Wq : (mtx == 1) ? Wk : (mtx == 2) ? Wv : Wo;
    unsigned short* Out = (mtx < 3) ? (Wqkv_t + (size_t)mtx * 1024 * 1024) : Wo_t;
    int tl = blockIdx.x;
    int tx = tl & 15, ty = tl >> 4;
    int t = threadIdx.x;
    int col = t & 63, rb = t >> 6;
#pragma unroll
    for (int rr = 0; rr < 16; ++rr) {
        int r = rb * 16 + rr;
        tile[r][col] = W[(size_t)(ty * 64 + r) * 1024 + tx * 64 + col];
    }
    __syncthreads();
#pragma unroll
    for (int rr = 0; rr < 16; ++rr) {
        int r = rb * 16 + rr;
        Out[(size_t)(tx * 64 + r) * 1024 + ty * 64 + col] = f2bf(tile[col][r]);
    }
}

// ---------------- kernel 3: QKV GEMM (8192x1024 @ 1024x3072) ----------------
__global__ __launch_bounds__(256) void gemm_qkv_kernel(
    const unsigned short* __restrict__ A, const unsigned short* __restrict__ Bt,
    unsigned short* __restrict__ Qg, unsigned short* __restrict__ Kg, unsigned short* __restrict__ Vt) {
    __shared__ __align__(16) unsigned short As[128 * 32];
    __shared__ __align__(16) unsigned short Bs[128 * 32];
    const int tid = threadIdx.x;
    const int w = tid >> 6, lane = tid & 63;
    const int quad = lane >> 4, l16 = lane & 15;
    const int m0 = blockIdx.y * 128, n0 = blockIdx.x * 128;
    const int mw = (w >> 1) * 64, nw = (w & 1) * 64;
    const int K = 1024;
    const int srow = lane >> 2;
    const int scol = (lane & 3) * 8;

    const f32x4 fzero = {0.f, 0.f, 0.f, 0.f};
    f32x4 acc[4][4];
#pragma unroll
    for (int i = 0; i < 4; ++i)
#pragma unroll
        for (int j = 0; j < 4; ++j) acc[i][j] = fzero;

    for (int k0 = 0; k0 < K; k0 += 32) {
        gl_lds16(A + (size_t)(m0 + w * 32 + srow) * K + k0 + scol,       As + (w * 32) * 32);
        gl_lds16(A + (size_t)(m0 + w * 32 + 16 + srow) * K + k0 + scol,  As + (w * 32 + 16) * 32);
        gl_lds16(Bt + (size_t)(n0 + w * 32 + srow) * K + k0 + scol,      Bs + (w * 32) * 32);
        gl_lds16(Bt + (size_t)(n0 + w * 32 + 16 + srow) * K + k0 + scol, Bs + (w * 32 + 16) * 32);
        __syncthreads();
        bf16x8 a[4], b[4];
#pragma unroll
        for (int i = 0; i < 4; ++i)
            a[i] = *(const bf16x8*)(As + (mw + i * 16 + l16) * 32 + quad * 8);
#pragma unroll
        for (int j = 0; j < 4; ++j)
            b[j] = *(const bf16x8*)(Bs + (nw + j * 16 + l16) * 32 + quad * 8);
#pragma unroll
        for (int i = 0; i < 4; ++i)
#pragma unroll
            for (int j = 0; j < 4; ++j)
                acc[i][j] = __builtin_amdgcn_mfma_f32_16x16x32_bf16(a[i], b[j], acc[i][j], 0, 0, 0);
        __syncthreads();
    }

#pragma unroll
    for (int j = 0; j < 4; ++j) {
        int gn = n0 + nw + j * 16 + l16;
        int tensor = gn >> 10;
        int nl = gn & 1023;
        int hh = nl >> 6, dd = nl & 63;
#pragma unroll
        for (int i = 0; i < 4; ++i) {
            int gmb = m0 + mw + i * 16 + quad * 4;
#pragma unroll
            for (int r = 0; r < 4; ++r) {
                int m = gmb + r;
                int bb = m >> 11, tt = m & 2047;
                unsigned short v = f2bf(acc[i][j][r]);
                size_t bhh = (size_t)(bb * 16 + hh);
                if (tensor == 0)      Qg[(bhh * 2048 + tt) * 64 + dd] = v;
                else if (tensor == 1) Kg[(bhh * 2048 + tt) * 64 + dd] = v;
                else                  Vt[(bhh * 64 + dd) * 2048 + tt] = v;
            }
        }
    }
}

// ---------------- kernel 4: flash attention (S^T formulation, no online max) ----
// Q,K: (b,h,t,d) bf16. Vt: (b,h,d,t) bf16. AO out: (b,t,h,d) bf16.
// Block: 4 waves, 128 q-rows (32/wave). 64 keys per iteration.
// LDS buffers hold MFMA fragments in lane order -> ds_read_b128 stride-1, conflict-free.
__global__ __launch_bounds__(256) void attn_kernel(
    const unsigned short* __restrict__ Qg, const unsigned short* __restrict__ Kg,
    const unsigned short* __restrict__ Vt, const int* __restrict__ mask,
    unsigned short* __restrict__ AO) {
    __shared__ __align__(16) unsigned short Kbuf[4096];     // 4 key-tiles x [dhalf][quad][l16][8]
    __shared__ __align__(16) unsigned short Vbuf[4096];     // [c][nd][quad][l16][8]
    __shared__ __align__(16) unsigned short Pbuf[4][2048];  // per-wave: [qi][c][quad][l16][8]
    __shared__ float li_lds[4][32];

    const int tid = threadIdx.x;
    const int w = tid >> 6, lane = tid & 63;
    const int quad = lane >> 4, l16 = lane & 15;
    const int bid = blockIdx.x;
    const int bh = bid >> 4;
    const int qt = bid & 15;
    const int b = bh >> 4, h = bh & 15;
    const size_t bh_td = (size_t)bh * 2048 * 64;
    const size_t bh_dt = (size_t)bh * 64 * 2048;
    const int q0w = qt * 128 + w * 32;

    // Q fragments (B-operand): [n=q=l16][k=d=quad*8+j], persisted in registers
    bf16x8 aq[2][2];
#pragma unroll
    for (int qi = 0; qi < 2; ++qi)
#pragma unroll
        for (int hh = 0; hh < 2; ++hh)
            aq[qi][hh] = *(const bf16x8*)(Qg + bh_td + (size_t)(q0w + qi * 16 + l16) * 64 + hh * 32 + quad * 8);

    // per-lane staging source offsets (lane i -> LDS base + 16*i)
    const int krow = lane & 15;
    const int kch = (lane >> 4) & 3;
    const unsigned short* Ksrc = Kg + bh_td + (size_t)(w * 16 + krow) * 64 + kch * 8;
    const unsigned short* Vsrc = Vt + bh_dt + (size_t)(w * 16 + krow) * 2048 + kch * 8;
    unsigned short* Kdst = Kbuf + w * 1024;
    unsigned short* Vdst = Vbuf + w * 512;

    const f32x4 fzero = {0.f, 0.f, 0.f, 0.f};
    f32x4 po[2][4];
#pragma unroll
    for (int qi = 0; qi < 2; ++qi)
#pragma unroll
        for (int nd = 0; nd < 4; ++nd) po[qi][nd] = fzero;
    float li[2] = {0.f, 0.f};
    const int* mrow = mask + b * 2048;

    for (int k0 = 0; k0 < 2048; k0 += 64) {
        __syncthreads();
        gl_lds16(Ksrc + (size_t)k0 * 64,      Kdst);          // tile w, dhalf 0
        gl_lds16(Ksrc + (size_t)k0 * 64 + 32, Kdst + 512);    // tile w, dhalf 1
        gl_lds16(Vsrc + k0,                   Vdst);          // chunk 0, nd=w
        gl_lds16(Vsrc + k0 + 32,              Vdst + 2048);   // chunk 1, nd=w
        __syncthreads();

        // ---- S^T = K @ Q^T per 16-key tile, exp, pack into P fragments ----
#pragma unroll
        for (int kt = 0; kt < 4; ++kt) {
            bf16x8 ka0 = *(const bf16x8*)(Kbuf + kt * 1024 + lane * 8);
            bf16x8 ka1 = *(const bf16x8*)(Kbuf + kt * 1024 + 512 + lane * 8);
            int4 mv = *(const int4*)(mrow + k0 + kt * 16 + quad * 4);
            float mb0 = mv.x ? 0.f : -1e30f;
            float mb1 = mv.y ? 0.f : -1e30f;
            float mb2 = mv.z ? 0.f : -1e30f;
            float mb3 = mv.w ? 0.f : -1e30f;
            int pidx = ((((kt & 1) << 1) | (quad >> 1)) * 16 + l16) * 8 + (quad & 1) * 4;
#pragma unroll
            for (int qi = 0; qi < 2; ++qi) {
                f32x4 st = __builtin_amdgcn_mfma_f32_16x16x32_bf16(ka0, aq[qi][0], fzero, 0, 0, 0);
                st = __builtin_amdgcn_mfma_f32_16x16x32_bf16(ka1, aq[qi][1], st, 0, 0, 0);
                float p0 = __builtin_amdgcn_exp2f(st[0] * SE + mb0);
                float p1 = __builtin_amdgcn_exp2f(st[1] * SE + mb1);
                float p2 = __builtin_amdgcn_exp2f(st[2] * SE + mb2);
                float p3 = __builtin_amdgcn_exp2f(st[3] * SE + mb3);
                li[qi] += (p0 + p1) + (p2 + p3);
                uint2 pk; pk.x = packbf(p0, p1); pk.y = packbf(p2, p3);
                *(uint2*)(Pbuf[w] + (qi * 2 + (kt >> 1)) * 512 + pidx) = pk;
            }
        }

        // ---- PV: O[q][d] += P @ V ----
#pragma unroll
        for (int c = 0; c < 2; ++c) {
            bf16x8 bv[4];
#pragma unroll
            for (int nd = 0; nd < 4; ++nd)
                bv[nd] = *(const bf16x8*)(Vbuf + (c * 4 + nd) * 512 + lane * 8);
#pragma unroll
            for (int qi = 0; qi < 2; ++qi) {
                bf16x8 ap = *(const bf16x8*)(Pbuf[w] + (qi * 2 + c) * 512 + lane * 8);
#pragma unroll
                for (int nd = 0; nd < 4; ++nd)
                    po[qi][nd] = __builtin_amdgcn_mfma_f32_16x16x32_bf16(ap, bv[nd], po[qi][nd], 0, 0, 0);
            }
        }
    }

    // ---- epilogue: reduce li across quads, transpose via LDS, write out ----
#pragma unroll
    for (int qi = 0; qi < 2; ++qi) {
        li[qi] += __shfl_xor(li[qi], 16, 64);
        li[qi] += __shfl_xor(li[qi], 32, 64);
        if (quad == 0) li_lds[w][qi * 16 + l16] = li[qi];
    }
    float linv[2][4];
#pragma unroll
    for (int qi = 0; qi < 2; ++qi)
#pragma unroll
        for (int r = 0; r < 4; ++r)
            linv[qi][r] = __builtin_amdgcn_rcpf(li_lds[w][qi * 16 + quad * 4 + r]);

#pragma unroll
    for (int qi = 0; qi < 2; ++qi)
#pragma unroll
        for (int r = 0; r < 4; ++r) {
            int q = q0w + qi * 16 + quad * 4 + r;
            size_t ob = (size_t)(b * 2048 + q) * 1024 + h * 64;
#pragma unroll
            for (int nd = 0; nd < 4; ++nd)
                AO[ob + nd * 16 + l16] = f2bf(po[qi][nd][r] * linv[qi][r]);
        }
}

// ---------------- kernel 5: output GEMM (8192x1024 @ 1024x1024) + bias ----------------
__global__ __launch_bounds__(256) void gemm_out_kernel(
    const unsigned short* __restrict__ A, const unsigned short* __restrict__ Bt,
    const float* __restrict__ bo, float* __restrict__ out) {
    __shared__ __align__(16) unsigned short As[128 * 32];
    __shared__ __align__(16) unsigned short Bs[128 * 32];
    const int tid = threadIdx.x;
    const int w = tid >> 6, lane = tid & 63;
    const int quad = lane >> 4, l16 = lane & 15;
    const int m0 = blockIdx.y * 128, n0 = blockIdx.x * 128;
    const int mw = (w >> 1) * 64, nw = (w & 1) * 64;
    const int K = 1024;
    const int srow = lane >> 2;
    const int scol = (lane & 3) * 8;

    const f32x4 fzero = {0.f, 0.f, 0.f, 0.f};
    f32x4 acc[4][4];
#pragma unroll
    for (int i = 0; i < 4; ++i)
#pragma unroll
        for (int j = 0; j < 4; ++j) acc[i][j] = fzero;

    for (int k0 = 0; k0 < K; k0 += 32) {
        gl_lds16(A + (size_t)(m0 + w * 32 + srow) * K + k0 + scol,       As + (w * 32) * 32);
        gl_lds16(A + (size_t)(m0 + w * 32 + 16 + srow) * K + k0 + scol,  As + (w * 32 + 16) * 32);
        gl_lds16(Bt + (size_t)(n0 + w * 32 + srow) * K + k0 + scol,      Bs + (w * 32) * 32);
        gl_lds16(Bt + (size_t)(n0 + w * 32 + 16 + srow) * K + k0 + scol, Bs + (w * 32 + 16) * 32);
        __syncthreads();
        bf16x8 a[4], b[4];
#pragma unroll
        for (int i = 0; i < 4; ++i)
            a[i] = *(const bf16x8*)(As + (mw + i * 16 + l16) * 32 + quad * 8);
#pragma unroll
        for (int j = 0; j < 4; ++j)
            b[j] = *(const bf16x8*)(Bs + (nw + j * 16 + l16) * 32 + quad * 8);
#pragma unroll
        for (int i = 0; i < 4; ++i)
#pragma unroll
            for (int j = 0; j < 4; ++j)
                acc[i][j] = __builtin_amdgcn_mfma_f32_16x16x32_bf16(a[i], b[j], acc[i][j], 0, 0, 0);
        __syncthreads();
    }

#pragma unroll
    for (int j = 0; j < 4; ++j) {
        int gn = n0 + nw + j * 16 + l16;
        float bias = bo[gn];
#pragma unroll
        for (int i = 0; i < 4; ++i) {
            int gmb = m0 + mw + i * 16 + quad * 4;
#pragma unroll
            for (int r = 0; r < 4; ++r)
                out[(size_t)(gmb + r) * 1024 + gn] = acc[i][j][r] + bias;
        }
    }
}

extern "C" void kernel_launch(void* const* d_in, const int* in_sizes, int n_in,
                              void* d_out, int out_size, void* d_ws, size_t ws_size,
                              hipStream_t stream) {
    const float* hs  = (const float*)d_in[0];
    const int* mask  = (const int*)d_in[1];
    const float* Wq  = (const float*)d_in[2];
    const float* Wk  = (const float*)d_in[3];
    const float* Wv  = (const float*)d_in[4];
    const float* Wo  = (const float*)d_in[5];
    const float* bo  = (const float*)d_in[6];
    float* out = (float*)d_out;

    char* ws = (char*)d_ws;
    unsigned short* hs_bf = (unsigned short*)(ws);                  // 16 MB
    unsigned short* wqkv  = (unsigned short*)(ws + 16777216);       // 6 MB
    unsigned short* wo_t  = (unsigned short*)(ws + 23068672);       // 2 MB
    unsigned short* Qg    = (unsigned short*)(ws + 25165824);       // 16 MB
    unsigned short* Kg    = (unsigned short*)(ws + 41943040);       // 16 MB
    unsigned short* Vt    = (unsigned short*)(ws + 58720256);       // 16 MB
    unsigned short* AO    = (unsigned short*)(ws + 75497472);       // 16 MB

    cvt_hs_kernel<<<8192, 256, 0, stream>>>((const float4*)hs, (ushort4*)hs_bf);
    wtrans_kernel<<<dim3(256, 4), 256, 0, stream>>>(Wq, Wk, Wv, Wo, wqkv, wo_t);
    gemm_qkv_kernel<<<dim3(24, 64), 256, 0, stream>>>(hs_bf, wqkv, Qg, Kg, Vt);
    attn_kernel<<<1024, 256, 0, stream>>>(Qg, Kg, Vt, mask, AO);
    gemm_out_kernel<<<dim3(8, 64), 256, 0, stream>>>(AO, wo_t, bo, out);
}

// Round 4
// 301.380 us; speedup vs baseline: 1.8716x; 1.1895x over previous
//
#include <hip/hip_runtime.h>
#include <hip/hip_bf16.h>

#define B_ 4
#define T_ 2048
#define C_ 1024
#define H_ 16
#define D_ 64
#define SCALE_ 0.125f
#define L2E 1.4426950408889634f
#define SE (SCALE_ * L2E)

typedef __attribute__((ext_vector_type(8))) short bf16x8;
typedef __attribute__((ext_vector_type(4))) float f32x4;

__device__ __forceinline__ unsigned short f2bf(float f) {
    union { float f; unsigned u; } v; v.f = f;
    unsigned r = v.u + 0x7fff + ((v.u >> 16) & 1);
    return (unsigned short)(r >> 16);
}

__device__ __forceinline__ unsigned pk2bf(float a, float b) {
    __hip_bfloat162 t = __float22bfloat162_rn(make_float2(a, b));
    union { __hip_bfloat162 h; unsigned u; } c; c.h = t;
    return c.u;
}

__device__ __forceinline__ void gl_lds16(const unsigned short* g, unsigned short* l) {
    __builtin_amdgcn_global_load_lds(
        (const __attribute__((address_space(1))) void*)g,
        (__attribute__((address_space(3))) void*)l,
        16, 0, 0);
}

// ---------------- kernel 1: hidden_states fp32 -> bf16 ----------------
__global__ void cvt_hs_kernel(const float4* __restrict__ in, ushort4* __restrict__ out) {
    int i = blockIdx.x * 256 + threadIdx.x;
    float4 v = in[i];
    ushort4 o;
    o.x = f2bf(v.x); o.y = f2bf(v.y); o.z = f2bf(v.z); o.w = f2bf(v.w);
    out[i] = o;
}

// ---------------- kernel 2: weight transpose+cast (W[k][n] -> Wt[n][k] bf16) ----
__global__ void wtrans_kernel(const float* __restrict__ Wq, const float* __restrict__ Wk,
                              const float* __restrict__ Wv, const float* __restrict__ Wo,
                              unsigned short* __restrict__ Wqkv_t, unsigned short* __restrict__ Wo_t) {
    __shared__ float tile[64][65];
    int mtx = blockIdx.y;
    const float* W = (mtx == 0) ? Wq : (mtx == 1) ? Wk : (mtx == 2) ? Wv : Wo;
    unsigned short* Out = (mtx < 3) ? (Wqkv_t + (size_t)mtx * 1024 * 1024) : Wo_t;
    int tl = blockIdx.x;
    int tx = tl & 15, ty = tl >> 4;
    int t = threadIdx.x;
    int col = t & 63, rb = t >> 6;
#pragma unroll
    for (int rr = 0; rr < 16; ++rr) {
        int r = rb * 16 + rr;
        tile[r][col] = W[(size_t)(ty * 64 + r) * 1024 + tx * 64 + col];
    }
    __syncthreads();
#pragma unroll
    for (int rr = 0; rr < 16; ++rr) {
        int r = rb * 16 + rr;
        Out[(size_t)(tx * 64 + r) * 1024 + ty * 64 + col] = f2bf(tile[col][r]);
    }
}

// ---------------- kernel 3: QKV GEMM (8192x1024 @ 1024x3072) ----------------
// Q -> (b,h,t,d). K -> fragment order Kf[bh][tile=tt>>4][dhalf=dd>>5][lane][j]
// (tile stride 1024, dhalf stride 512), lane=((dd>>3)&3)*16+(tt&15), j=dd&7.
// V -> fragment order Vf[bh][chunk=tt>>5][nd=dd>>4][lane][j],
// lane=((tt>>3)&3)*16+(dd&15), j=tt&7.
__global__ __launch_bounds__(256) void gemm_qkv_kernel(
    const unsigned short* __restrict__ A, const unsigned short* __restrict__ Bt,
    unsigned short* __restrict__ Qg, unsigned short* __restrict__ Kf, unsigned short* __restrict__ Vf) {
    __shared__ __align__(16) unsigned short As[128 * 32];
    __shared__ __align__(16) unsigned short Bs[128 * 32];
    const int tid = threadIdx.x;
    const int w = tid >> 6, lane = tid & 63;
    const int quad = lane >> 4, l16 = lane & 15;
    const int m0 = blockIdx.y * 128, n0 = blockIdx.x * 128;
    const int mw = (w >> 1) * 64, nw = (w & 1) * 64;
    const int K = 1024;
    const int srow = lane >> 2;
    const int scol = (lane & 3) * 8;

    const f32x4 fzero = {0.f, 0.f, 0.f, 0.f};
    f32x4 acc[4][4];
#pragma unroll
    for (int i = 0; i < 4; ++i)
#pragma unroll
        for (int j = 0; j < 4; ++j) acc[i][j] = fzero;

    for (int k0 = 0; k0 < K; k0 += 32) {
        gl_lds16(A + (size_t)(m0 + w * 32 + srow) * K + k0 + scol,       As + (w * 32) * 32);
        gl_lds16(A + (size_t)(m0 + w * 32 + 16 + srow) * K + k0 + scol,  As + (w * 32 + 16) * 32);
        gl_lds16(Bt + (size_t)(n0 + w * 32 + srow) * K + k0 + scol,      Bs + (w * 32) * 32);
        gl_lds16(Bt + (size_t)(n0 + w * 32 + 16 + srow) * K + k0 + scol, Bs + (w * 32 + 16) * 32);
        __syncthreads();
        bf16x8 a[4], b[4];
#pragma unroll
        for (int i = 0; i < 4; ++i)
            a[i] = *(const bf16x8*)(As + (mw + i * 16 + l16) * 32 + quad * 8);
#pragma unroll
        for (int j = 0; j < 4; ++j)
            b[j] = *(const bf16x8*)(Bs + (nw + j * 16 + l16) * 32 + quad * 8);
#pragma unroll
        for (int i = 0; i < 4; ++i)
#pragma unroll
            for (int j = 0; j < 4; ++j)
                acc[i][j] = __builtin_amdgcn_mfma_f32_16x16x32_bf16(a[i], b[j], acc[i][j], 0, 0, 0);
        __syncthreads();
    }

#pragma unroll
    for (int j = 0; j < 4; ++j) {
        int gn = n0 + nw + j * 16 + l16;
        int tensor = gn >> 10;
        int nl = gn & 1023;
        int hh = nl >> 6, dd = nl & 63;
#pragma unroll
        for (int i = 0; i < 4; ++i) {
            int gmb = m0 + mw + i * 16 + quad * 4;
            int bb = gmb >> 11;
            size_t bhh = (size_t)(bb * 16 + hh);
            if (tensor == 0) {
#pragma unroll
                for (int r = 0; r < 4; ++r) {
                    int tt = (gmb + r) & 2047;
                    Qg[(bhh * 2048 + tt) * 64 + dd] = f2bf(acc[i][j][r]);
                }
            } else if (tensor == 1) {
#pragma unroll
                for (int r = 0; r < 4; ++r) {
                    int tt = (gmb + r) & 2047;
                    Kf[bhh * 131072 + (size_t)(tt >> 4) * 1024 + (dd >> 5) * 512 +
                       (((dd >> 3) & 3) * 16 + (tt & 15)) * 8 + (dd & 7)] = f2bf(acc[i][j][r]);
                }
            } else {
                int tt = gmb & 2047;
                ushort4 v4;
                v4.x = f2bf(acc[i][j][0]); v4.y = f2bf(acc[i][j][1]);
                v4.z = f2bf(acc[i][j][2]); v4.w = f2bf(acc[i][j][3]);
                *(ushort4*)(Vf + bhh * 131072 + (size_t)(tt >> 5) * 2048 + (dd >> 4) * 512 +
                            (((tt >> 3) & 3) * 16 + (dd & 15)) * 8 + (tt & 7)) = v4;
            }
        }
    }
}

// ---------------- kernel 4: flash attention (barrier-free, S^T, no online max) ----
// Q: (b,h,t,d) bf16. Kf/Vf: fragment order (see gemm_qkv). AO out: (b,t,h,d) bf16.
// 4 waves/block, each wave owns 32 q-rows; 64 keys/iter; K/V frags loaded
// directly global->VGPR (coalesced 1KB per load, L1/L2-cached, shared by
// 4 waves x 16 blocks). Only P transits (per-wave) LDS. Zero __syncthreads.
__global__ __launch_bounds__(256) void attn_kernel(
    const unsigned short* __restrict__ Qg, const unsigned short* __restrict__ Kf,
    const unsigned short* __restrict__ Vf, const int* __restrict__ mask,
    unsigned short* __restrict__ AO) {
    __shared__ __align__(16) unsigned short Pbuf[4][2048];
    __shared__ float li_lds[4][32];

    const int tid = threadIdx.x;
    const int w = tid >> 6, lane = tid & 63;
    const int quad = lane >> 4, l16 = lane & 15;
    const int bid = blockIdx.x;
    const int bh = bid >> 4;
    const int qt = bid & 15;
    const int b = bh >> 4, h = bh & 15;
    const size_t bh_td = (size_t)bh * (2048 * 64);
    const int q0w = qt * 128 + w * 32;

    // Q fragments (B-operand): [n=q=l16][k=d=quad*8+j]
    bf16x8 aq[2][2];
#pragma unroll
    for (int qi = 0; qi < 2; ++qi)
#pragma unroll
        for (int hh = 0; hh < 2; ++hh)
            aq[qi][hh] = *(const bf16x8*)(Qg + bh_td + (size_t)(q0w + qi * 16 + l16) * 64 + hh * 32 + quad * 8);

    const unsigned short* Kp = Kf + bh_td + lane * 8;
    const unsigned short* Vp = Vf + bh_td + lane * 8;
    const int* mrow = mask + b * 2048;

    const f32x4 fzero = {0.f, 0.f, 0.f, 0.f};
    f32x4 po[2][4];
#pragma unroll
    for (int qi = 0; qi < 2; ++qi)
#pragma unroll
        for (int nd = 0; nd < 4; ++nd) po[qi][nd] = fzero;
    float li[2] = {0.f, 0.f};

    for (int k0 = 0; k0 < 2048; k0 += 64) {
        const int tb = (k0 >> 4) * 1024;
        // K fragments: A-operand [m=key=l16][k=d=quad*8+j]
        bf16x8 ka0[4], ka1[4];
#pragma unroll
        for (int kt = 0; kt < 4; ++kt) {
            ka0[kt] = *(const bf16x8*)(Kp + tb + kt * 1024);
            ka1[kt] = *(const bf16x8*)(Kp + tb + kt * 1024 + 512);
        }

        // ---- S^T = K @ Q^T per 16-key tile, exp, pack into P fragments ----
#pragma unroll
        for (int kt = 0; kt < 4; ++kt) {
            int4 mv = *(const int4*)(mrow + k0 + kt * 16 + quad * 4);
            float mb0 = mv.x ? 0.f : -1e30f;
            float mb1 = mv.y ? 0.f : -1e30f;
            float mb2 = mv.z ? 0.f : -1e30f;
            float mb3 = mv.w ? 0.f : -1e30f;
            int pidx = ((((kt & 1) << 1) | (quad >> 1)) * 16 + l16) * 8 + (quad & 1) * 4;
#pragma unroll
            for (int qi = 0; qi < 2; ++qi) {
                f32x4 st = __builtin_amdgcn_mfma_f32_16x16x32_bf16(ka0[kt], aq[qi][0], fzero, 0, 0, 0);
                st = __builtin_amdgcn_mfma_f32_16x16x32_bf16(ka1[kt], aq[qi][1], st, 0, 0, 0);
                float p0 = __builtin_amdgcn_exp2f(st[0] * SE + mb0);
                float p1 = __builtin_amdgcn_exp2f(st[1] * SE + mb1);
                float p2 = __builtin_amdgcn_exp2f(st[2] * SE + mb2);
                float p3 = __builtin_amdgcn_exp2f(st[3] * SE + mb3);
                li[qi] += (p0 + p1) + (p2 + p3);
                uint2 pk; pk.x = pk2bf(p0, p1); pk.y = pk2bf(p2, p3);
                *(uint2*)(Pbuf[w] + (qi * 2 + (kt >> 1)) * 512 + pidx) = pk;
            }
        }

        // V fragments: B-operand [n=d=l16(+16*nd)][k=key=quad*8+j]
        bf16x8 bv[2][4];
#pragma unroll
        for (int c = 0; c < 2; ++c)
#pragma unroll
            for (int nd = 0; nd < 4; ++nd)
                bv[c][nd] = *(const bf16x8*)(Vp + ((k0 >> 5) + c) * 2048 + nd * 512);

        asm volatile("s_waitcnt lgkmcnt(0)" ::: "memory");

        // ---- PV: O[q][d] += P @ V ----
#pragma unroll
        for (int c = 0; c < 2; ++c)
#pragma unroll
            for (int qi = 0; qi < 2; ++qi) {
                bf16x8 ap = *(const bf16x8*)(Pbuf[w] + (qi * 2 + c) * 512 + lane * 8);
#pragma unroll
                for (int nd = 0; nd < 4; ++nd)
                    po[qi][nd] = __builtin_amdgcn_mfma_f32_16x16x32_bf16(ap, bv[c][nd], po[qi][nd], 0, 0, 0);
            }
    }

    // ---- epilogue: reduce li across quads (per-wave), write AO (b,t,h,d) ----
#pragma unroll
    for (int qi = 0; qi < 2; ++qi) {
        li[qi] += __shfl_xor(li[qi], 16, 64);
        li[qi] += __shfl_xor(li[qi], 32, 64);
        if (quad == 0) li_lds[w][qi * 16 + l16] = li[qi];
    }
    asm volatile("s_waitcnt lgkmcnt(0)" ::: "memory");
    float linv[2][4];
#pragma unroll
    for (int qi = 0; qi < 2; ++qi)
#pragma unroll
        for (int r = 0; r < 4; ++r)
            linv[qi][r] = __builtin_amdgcn_rcpf(li_lds[w][qi * 16 + quad * 4 + r]);

#pragma unroll
    for (int qi = 0; qi < 2; ++qi)
#pragma unroll
        for (int r = 0; r < 4; ++r) {
            int q = q0w + qi * 16 + quad * 4 + r;
            size_t ob = (size_t)(b * 2048 + q) * 1024 + h * 64;
#pragma unroll
            for (int nd = 0; nd < 4; ++nd)
                AO[ob + nd * 16 + l16] = f2bf(po[qi][nd][r] * linv[qi][r]);
        }
}

// ---------------- kernel 5: output GEMM (8192x1024 @ 1024x1024) + bias ----------------
__global__ __launch_bounds__(256) void gemm_out_kernel(
    const unsigned short* __restrict__ A, const unsigned short* __restrict__ Bt,
    const float* __restrict__ bo, float* __restrict__ out) {
    __shared__ __align__(16) unsigned short As[128 * 32];
    __shared__ __align__(16) unsigned short Bs[128 * 32];
    const int tid = threadIdx.x;
    const int w = tid >> 6, lane = tid & 63;
    const int quad = lane >> 4, l16 = lane & 15;
    const int m0 = blockIdx.y * 128, n0 = blockIdx.x * 128;
    const int mw = (w >> 1) * 64, nw = (w & 1) * 64;
    const int K = 1024;
    const int srow = lane >> 2;
    const int scol = (lane & 3) * 8;

    const f32x4 fzero = {0.f, 0.f, 0.f, 0.f};
    f32x4 acc[4][4];
#pragma unroll
    for (int i = 0; i < 4; ++i)
#pragma unroll
        for (int j = 0; j < 4; ++j) acc[i][j] = fzero;

    for (int k0 = 0; k0 < K; k0 += 32) {
        gl_lds16(A + (size_t)(m0 + w * 32 + srow) * K + k0 + scol,       As + (w * 32) * 32);
        gl_lds16(A + (size_t)(m0 + w * 32 + 16 + srow) * K + k0 + scol,  As + (w * 32 + 16) * 32);
        gl_lds16(Bt + (size_t)(n0 + w * 32 + srow) * K + k0 + scol,      Bs + (w * 32) * 32);
        gl_lds16(Bt + (size_t)(n0 + w * 32 + 16 + srow) * K + k0 + scol, Bs + (w * 32 + 16) * 32);
        __syncthreads();
        bf16x8 a[4], b[4];
#pragma unroll
        for (int i = 0; i < 4; ++i)
            a[i] = *(const bf16x8*)(As + (mw + i * 16 + l16) * 32 + quad * 8);
#pragma unroll
        for (int j = 0; j < 4; ++j)
            b[j] = *(const bf16x8*)(Bs + (nw + j * 16 + l16) * 32 + quad * 8);
#pragma unroll
        for (int i = 0; i < 4; ++i)
#pragma unroll
            for (int j = 0; j < 4; ++j)
                acc[i][j] = __builtin_amdgcn_mfma_f32_16x16x32_bf16(a[i], b[j], acc[i][j], 0, 0, 0);
        __syncthreads();
    }

#pragma unroll
    for (int j = 0; j < 4; ++j) {
        int gn = n0 + nw + j * 16 + l16;
        float bias = bo[gn];
#pragma unroll
        for (int i = 0; i < 4; ++i) {
            int gmb = m0 + mw + i * 16 + quad * 4;
#pragma unroll
            for (int r = 0; r < 4; ++r)
                out[(size_t)(gmb + r) * 1024 + gn] = acc[i][j][r] + bias;
        }
    }
}

extern "C" void kernel_launch(void* const* d_in, const int* in_sizes, int n_in,
                              void* d_out, int out_size, void* d_ws, size_t ws_size,
                              hipStream_t stream) {
    const float* hs  = (const float*)d_in[0];
    const int* mask  = (const int*)d_in[1];
    const float* Wq  = (const float*)d_in[2];
    const float* Wk  = (const float*)d_in[3];
    const float* Wv  = (const float*)d_in[4];
    const float* Wo  = (const float*)d_in[5];
    const float* bo  = (const float*)d_in[6];
    float* out = (float*)d_out;

    char* ws = (char*)d_ws;
    unsigned short* hs_bf = (unsigned short*)(ws);                  // 16 MB
    unsigned short* wqkv  = (unsigned short*)(ws + 16777216);       // 6 MB
    unsigned short* wo_t  = (unsigned short*)(ws + 23068672);       // 2 MB
    unsigned short* Qg    = (unsigned short*)(ws + 25165824);       // 16 MB
    unsigned short* Kf    = (unsigned short*)(ws + 41943040);       // 16 MB
    unsigned short* Vf    = (unsigned short*)(ws + 58720256);       // 16 MB
    unsigned short* AO    = (unsigned short*)(ws + 75497472);       // 16 MB

    cvt_hs_kernel<<<8192, 256, 0, stream>>>((const float4*)hs, (ushort4*)hs_bf);
    wtrans_kernel<<<dim3(256, 4), 256, 0, stream>>>(Wq, Wk, Wv, Wo, wqkv, wo_t);
    gemm_qkv_kernel<<<dim3(24, 64), 256, 0, stream>>>(hs_bf, wqkv, Qg, Kf, Vf);
    attn_kernel<<<1024, 256, 0, stream>>>(Qg, Kf, Vf, mask, AO);
    gemm_out_kernel<<<dim3(8, 64), 256, 0, stream>>>(AO, wo_t, bo, out);
}